// Round 1
// baseline (1135.784 us; speedup 1.0000x reference)
//
#include <hip/hip_runtime.h>
#include <cstdint>

#define NN 50000
#define NE 640000
#define NG 128
#define HD 128
#define FN 64
#define FE 16
#define FL 200
#define FPOC 100
#define NSTACK 3

// ---------------- CSR build ----------------

__global__ void count_kernel(const int* __restrict__ ei, int* __restrict__ cnt) {
    int e = blockIdx.x * 256 + threadIdx.x;
    if (e < NE) atomicAdd(&cnt[ei[NE + e]], 1);
}

__global__ void scan_kernel(const int* __restrict__ cnt, int* __restrict__ row_ptr,
                            float* __restrict__ degf, int n) {
    __shared__ int part[1024];
    int t = threadIdx.x;
    const int C = (n + 1023) / 1024;
    int s0 = t * C;
    int e0 = min(s0 + C, n);
    int sum = 0;
    for (int i = s0; i < e0; ++i) sum += cnt[i];
    part[t] = sum;
    __syncthreads();
    for (int off = 1; off < 1024; off <<= 1) {
        int v = (t >= off) ? part[t - off] : 0;
        __syncthreads();
        part[t] += v;
        __syncthreads();
    }
    int run = part[t] - sum;  // exclusive prefix
    for (int i = s0; i < e0; ++i) {
        row_ptr[i] = run;
        int c = cnt[i];
        degf[i] = (float)c;
        run += c;
    }
    if (s0 < n && e0 == n) row_ptr[n] = run;
}

__global__ void fill_kernel(const int* __restrict__ ei, const int* __restrict__ row_ptr,
                            int* __restrict__ fill, int* __restrict__ csr) {
    int e = blockIdx.x * 256 + threadIdx.x;
    if (e < NE) {
        int s = ei[e];
        int d = ei[NE + e];
        int p = row_ptr[d] + atomicAdd(&fill[d], 1);
        csr[p] = s;
    }
}

__global__ void sege_kernel(const int* __restrict__ ei, const float* __restrict__ ea,
                            float* __restrict__ segE) {
    int t = blockIdx.x * 256 + threadIdx.x;
    if (t < NE * FE) {
        int e = t >> 4;
        int f = t & 15;
        int d = ei[NE + e];
        atomicAdd(&segE[d * FE + f], ea[t]);
    }
}

// ---------------- dense GEMM: C[n,128] = A[n,K] @ W[K,128] (+bias) ----------------

__global__ __launch_bounds__(256) void gemm128(const float* __restrict__ A,
                                               const float* __restrict__ W,
                                               const float* __restrict__ bias,
                                               float* __restrict__ C, int n, int K) {
    __shared__ float As[16][72];   // transposed tile [k][row], 64 rows
    __shared__ float Bs[16][128];
    int tid = threadIdx.x;
    int row0 = blockIdx.x * 64;
    int tc = (tid & 31) * 4;       // col base (4 cols)
    int tr = (tid >> 5) * 8;       // row base (8 rows)
    float acc[8][4];
#pragma unroll
    for (int r = 0; r < 8; ++r)
#pragma unroll
        for (int c = 0; c < 4; ++c) acc[r][c] = 0.f;

    for (int k0 = 0; k0 < K; k0 += 16) {
        {
            int r = tid >> 2;            // 0..63
            int kk = (tid & 3) * 4;      // 0,4,8,12
            int gr = row0 + r;
            float4 av = make_float4(0.f, 0.f, 0.f, 0.f);
            if (gr < n) av = *(const float4*)(A + (size_t)gr * K + k0 + kk);
            As[kk + 0][r] = av.x;
            As[kk + 1][r] = av.y;
            As[kk + 2][r] = av.z;
            As[kk + 3][r] = av.w;
        }
        {
            int bk = tid >> 5;           // 0..7
            int bc = (tid & 31) * 4;
            *(float4*)&Bs[bk][bc]     = *(const float4*)(W + (size_t)(k0 + bk) * HD + bc);
            *(float4*)&Bs[bk + 8][bc] = *(const float4*)(W + (size_t)(k0 + bk + 8) * HD + bc);
        }
        __syncthreads();
#pragma unroll
        for (int kk2 = 0; kk2 < 16; ++kk2) {
            float4 b = *(float4*)&Bs[kk2][tc];
            float4 a0 = *(float4*)&As[kk2][tr];
            float4 a1 = *(float4*)&As[kk2][tr + 4];
            float a[8] = {a0.x, a0.y, a0.z, a0.w, a1.x, a1.y, a1.z, a1.w};
#pragma unroll
            for (int r = 0; r < 8; ++r) {
                acc[r][0] += a[r] * b.x;
                acc[r][1] += a[r] * b.y;
                acc[r][2] += a[r] * b.z;
                acc[r][3] += a[r] * b.w;
            }
        }
        __syncthreads();
    }
#pragma unroll
    for (int r = 0; r < 8; ++r) {
        int gr = row0 + tr + r;
        if (gr < n) {
            float4 o = make_float4(acc[r][0], acc[r][1], acc[r][2], acc[r][3]);
            if (bias) {
                o.x += bias[tc + 0];
                o.y += bias[tc + 1];
                o.z += bias[tc + 2];
                o.w += bias[tc + 3];
            }
            *(float4*)(C + (size_t)gr * HD + tc) = o;
        }
    }
}

// ---------------- fused aggregate: out[v] = relu( sum_{e:dst=v} xm[src] + segE[v]@We
//                                        + deg[v]*(bm+be) + selfadd[v] ) ----------------

__global__ __launch_bounds__(256) void agg_kernel(
    const int* __restrict__ row_ptr, const int* __restrict__ csr,
    const float* __restrict__ xm, const float* __restrict__ selfadd,
    const float* __restrict__ segE, const float* __restrict__ We,
    const float* __restrict__ bm, const float* __restrict__ be,
    const float* __restrict__ degf, float* __restrict__ out, int n) {
    __shared__ float WeS[FE * HD];
    for (int i = threadIdx.x; i < FE * HD; i += 256) WeS[i] = We[i];
    __syncthreads();
    int v = blockIdx.x * 2 + (threadIdx.x >> 7);
    int f = threadIdx.x & 127;
    if (v >= n) return;
    int beg = row_ptr[v], end = row_ptr[v + 1];
    float s = 0.f;
    for (int j = beg; j < end; ++j) {
        int u = csr[j];
        s += xm[(size_t)u * HD + f];
    }
    float et = degf[v] * (bm[f] + be[f]);
    const float* se = &segE[v * FE];
#pragma unroll
    for (int k = 0; k < FE; ++k) et += se[k] * WeS[k * HD + f];
    float r = s + et + selfadd[(size_t)v * HD + f];
    out[(size_t)v * HD + f] = fmaxf(r, 0.f);
}

// ---------------- mean pool (batch is sorted) ----------------

__global__ void pool_kernel(const float* __restrict__ h, const int* __restrict__ batch,
                            float* __restrict__ pooled, int n) {
    int g = blockIdx.x;
    int f = threadIdx.x;
    int lo = 0, hi = n;
    while (lo < hi) { int m = (lo + hi) >> 1; if (batch[m] < g) lo = m + 1; else hi = m; }
    int s = lo;
    lo = s; hi = n;
    while (lo < hi) { int m = (lo + hi) >> 1; if (batch[m] < g + 1) lo = m + 1; else hi = m; }
    int e = lo;
    float acc = 0.f;
    for (int v = s; v < e; ++v) acc += h[(size_t)v * HD + f];
    float c = (float)(e - s);
    pooled[g * HD + f] = acc / fmaxf(c, 1.f);
}

// ---------------- fusion head ----------------

__global__ void head_kernel(const float* __restrict__ pooled, const float* __restrict__ lf,
                            const float* __restrict__ pfe, const float* __restrict__ Wl,
                            const float* __restrict__ bl, const float* __restrict__ Wp,
                            const float* __restrict__ bp, const float* __restrict__ Wf,
                            const float* __restrict__ bfv, const float* __restrict__ Wo,
                            const float* __restrict__ bo, float* __restrict__ out) {
    __shared__ float cat[3 * HD];
    __shared__ float red[HD];
    int g = blockIdx.x, j = threadIdx.x;
    cat[j] = pooled[g * HD + j];
    float s = bl[j];
    for (int k = 0; k < FL; ++k) s += lf[g * FL + k] * Wl[k * HD + j];
    cat[HD + j] = s;
    s = bp[j];
    for (int k = 0; k < FPOC; ++k) s += pfe[g * FPOC + k] * Wp[k * HD + j];
    cat[2 * HD + j] = s;
    __syncthreads();
    float fj = bfv[j];
    for (int k = 0; k < 3 * HD; ++k) fj += cat[k] * Wf[k * HD + j];
    red[j] = fj * Wo[j];
    __syncthreads();
    for (int off = 64; off > 0; off >>= 1) {
        if (j < off) red[j] += red[j + off];
        __syncthreads();
    }
    if (j == 0) out[g] = red[0] + bo[0];
}

// ---------------- launch ----------------

extern "C" void kernel_launch(void* const* d_in, const int* in_sizes, int n_in,
                              void* d_out, int out_size, void* d_ws, size_t ws_size,
                              hipStream_t stream) {
    const float* x       = (const float*)d_in[0];
    const int*   ei      = (const int*)d_in[1];
    const float* ea      = (const float*)d_in[2];
    const int*   batch   = (const int*)d_in[3];
    const float* lf      = (const float*)d_in[4];
    const float* pfe     = (const float*)d_in[5];
    const float* W1_msg  = (const float*)d_in[6];
    const float* b1_msg  = (const float*)d_in[7];
    const float* W1_edge = (const float*)d_in[8];
    const float* b1_edge = (const float*)d_in[9];
    const float* W1_self = (const float*)d_in[10];
    const float* b1_self = (const float*)d_in[11];
    const float* Wk_msg  = (const float*)d_in[12];
    const float* bk_msg  = (const float*)d_in[13];
    const float* Wk_edge = (const float*)d_in[14];
    const float* bk_edge = (const float*)d_in[15];
    const float* Wl      = (const float*)d_in[16];
    const float* bl      = (const float*)d_in[17];
    const float* Wp      = (const float*)d_in[18];
    const float* bp      = (const float*)d_in[19];
    const float* Wf      = (const float*)d_in[20];
    const float* bfv     = (const float*)d_in[21];
    const float* Wo      = (const float*)d_in[22];
    const float* bo      = (const float*)d_in[23];

    char* wsp = (char*)d_ws;
    size_t off = 0;
    auto carve = [&](size_t bytes) -> void* {
        char* p = wsp + off;
        off += (bytes + 255) & ~(size_t)255;
        return (void*)p;
    };
    int*   cnt     = (int*)carve((size_t)NN * 4);
    int*   row_ptr = (int*)carve((size_t)(NN + 1) * 4);
    int*   fill    = (int*)carve((size_t)NN * 4);
    float* degf    = (float*)carve((size_t)NN * 4);
    int*   csr     = (int*)carve((size_t)NE * 4);
    float* segE    = (float*)carve((size_t)NN * FE * 4);
    float* bufA    = (float*)carve((size_t)NN * HD * 4);
    float* bufB    = (float*)carve((size_t)NN * HD * 4);
    float* bufC    = (float*)carve((size_t)NN * HD * 4);
    float* pooled  = (float*)carve((size_t)NG * HD * 4);

    hipMemsetAsync(cnt, 0, (size_t)NN * 4, stream);
    hipMemsetAsync(fill, 0, (size_t)NN * 4, stream);
    hipMemsetAsync(segE, 0, (size_t)NN * FE * 4, stream);

    count_kernel<<<(NE + 255) / 256, 256, 0, stream>>>(ei, cnt);
    scan_kernel<<<1, 1024, 0, stream>>>(cnt, row_ptr, degf, NN);
    fill_kernel<<<(NE + 255) / 256, 256, 0, stream>>>(ei, row_ptr, fill, csr);
    sege_kernel<<<(NE * FE + 255) / 256, 256, 0, stream>>>(ei, ea, segE);

    dim3 ggrid((NN + 63) / 64);
    // conv1: xm = x@W1_msg (bias folded via deg); selfo = x@W1_self + b1_self
    gemm128<<<ggrid, 256, 0, stream>>>(x, W1_msg, nullptr, bufC, NN, FN);
    gemm128<<<ggrid, 256, 0, stream>>>(x, W1_self, b1_self, bufB, NN, FN);
    agg_kernel<<<(NN + 1) / 2, 256, 0, stream>>>(row_ptr, csr, bufC, bufB, segE, W1_edge,
                                                 b1_msg, b1_edge, degf, bufA, NN);

    float* hcur = bufA;
    float* hnext = bufB;
    for (int i = 0; i < NSTACK; ++i) {
        gemm128<<<ggrid, 256, 0, stream>>>(hcur, Wk_msg + (size_t)i * HD * HD, nullptr, bufC,
                                           NN, HD);
        agg_kernel<<<(NN + 1) / 2, 256, 0, stream>>>(row_ptr, csr, bufC, hcur, segE,
                                                     Wk_edge + (size_t)i * FE * HD,
                                                     bk_msg + i * HD, bk_edge + i * HD, degf,
                                                     hnext, NN);
        float* t = hcur; hcur = hnext; hnext = t;
    }

    pool_kernel<<<NG, HD, 0, stream>>>(hcur, batch, pooled, NN);
    head_kernel<<<NG, HD, 0, stream>>>(pooled, lf, pfe, Wl, bl, Wp, bp, Wf, bfv, Wo, bo,
                                       (float*)d_out);
}

// Round 2
// 644.073 us; speedup vs baseline: 1.7634x; 1.7634x over previous
//
#include <hip/hip_runtime.h>
#include <cstdint>

#define NN 50000
#define NE 640000
#define NG 128
#define HD 128
#define FN 64
#define FE 16
#define FL 200
#define FPOC 100
#define NSTACK 3

// ---------------- CSR build ----------------

__global__ void count_kernel(const int* __restrict__ ei, int* __restrict__ cnt) {
    int e = blockIdx.x * 256 + threadIdx.x;
    if (e < NE) atomicAdd(&cnt[ei[NE + e]], 1);
}

// coalesced 3-phase exclusive scan of cnt[NN] -> row_ptr, degf
__global__ void bsum_kernel(const int* __restrict__ cnt, int* __restrict__ bsum) {
    __shared__ int s[256];
    int t = threadIdx.x;
    int i = blockIdx.x * 256 + t;
    int v = (i < NN) ? cnt[i] : 0;
    s[t] = v;
    __syncthreads();
    for (int off = 128; off > 0; off >>= 1) {
        if (t < off) s[t] += s[t + off];
        __syncthreads();
    }
    if (t == 0) bsum[blockIdx.x] = s[0];
}

__global__ void bscan_kernel(const int* __restrict__ bsum, int* __restrict__ bpre, int nb) {
    __shared__ int s[256];
    int t = threadIdx.x;
    int v = (t < nb) ? bsum[t] : 0;
    s[t] = v;
    __syncthreads();
    for (int off = 1; off < 256; off <<= 1) {
        int w = (t >= off) ? s[t - off] : 0;
        __syncthreads();
        s[t] += w;
        __syncthreads();
    }
    if (t < nb) bpre[t] = s[t] - v;
}

__global__ void rowptr_kernel(const int* __restrict__ cnt, const int* __restrict__ bpre,
                              int* __restrict__ row_ptr, float* __restrict__ degf) {
    __shared__ int s[256];
    int t = threadIdx.x;
    int i = blockIdx.x * 256 + t;
    int v = (i < NN) ? cnt[i] : 0;
    s[t] = v;
    __syncthreads();
    for (int off = 1; off < 256; off <<= 1) {
        int w = (t >= off) ? s[t - off] : 0;
        __syncthreads();
        s[t] += w;
        __syncthreads();
    }
    if (i < NN) {
        row_ptr[i] = s[t] - v + bpre[blockIdx.x];
        degf[i] = (float)v;
    }
    if (i == 0) row_ptr[NN] = NE;
}

__global__ void fill_kernel(const int* __restrict__ ei, const int* __restrict__ row_ptr,
                            int* __restrict__ fill, int* __restrict__ csr_s,
                            int* __restrict__ csr_e) {
    int e = blockIdx.x * 256 + threadIdx.x;
    if (e < NE) {
        int s = ei[e];
        int d = ei[NE + e];
        int p = row_ptr[d] + atomicAdd(&fill[d], 1);
        csr_s[p] = s;
        csr_e[p] = e;
    }
}

// segE[v,f] = sum over in-edges of edge_attr[e,f]  (gather, no atomics)
__global__ __launch_bounds__(256) void sege_kernel(
    const int* __restrict__ row_ptr, const int* __restrict__ csr_e,
    const float* __restrict__ ea, float* __restrict__ segE) {
    int node = blockIdx.x * 16 + (threadIdx.x >> 4);
    int f = threadIdx.x & 15;
    if (node >= NN) return;
    int beg = row_ptr[node], end = row_ptr[node + 1];
    float a0 = 0.f, a1 = 0.f;
    int j = beg;
    for (; j + 1 < end; j += 2) {
        int e0 = csr_e[j], e1 = csr_e[j + 1];
        a0 += ea[(size_t)e0 * FE + f];
        a1 += ea[(size_t)e1 * FE + f];
    }
    if (j < end) a0 += ea[(size_t)csr_e[j] * FE + f];
    segE[node * FE + f] = a0 + a1;
}

// ---------------- dense GEMM: C[n,128] = A[n,K] @ W[K,128] (+bias) ----------------

__global__ __launch_bounds__(256) void gemm128(const float* __restrict__ A,
                                               const float* __restrict__ W,
                                               const float* __restrict__ bias,
                                               float* __restrict__ C, int n, int K) {
    __shared__ float As[16][72];
    __shared__ float Bs[16][128];
    int tid = threadIdx.x;
    int row0 = blockIdx.x * 64;
    int tc = (tid & 31) * 4;
    int tr = (tid >> 5) * 8;
    float acc[8][4];
#pragma unroll
    for (int r = 0; r < 8; ++r)
#pragma unroll
        for (int c = 0; c < 4; ++c) acc[r][c] = 0.f;

    for (int k0 = 0; k0 < K; k0 += 16) {
        {
            int r = tid >> 2;
            int kk = (tid & 3) * 4;
            int gr = row0 + r;
            float4 av = make_float4(0.f, 0.f, 0.f, 0.f);
            if (gr < n) av = *(const float4*)(A + (size_t)gr * K + k0 + kk);
            As[kk + 0][r] = av.x;
            As[kk + 1][r] = av.y;
            As[kk + 2][r] = av.z;
            As[kk + 3][r] = av.w;
        }
        {
            int bk = tid >> 5;
            int bc = (tid & 31) * 4;
            *(float4*)&Bs[bk][bc]     = *(const float4*)(W + (size_t)(k0 + bk) * HD + bc);
            *(float4*)&Bs[bk + 8][bc] = *(const float4*)(W + (size_t)(k0 + bk + 8) * HD + bc);
        }
        __syncthreads();
#pragma unroll
        for (int kk2 = 0; kk2 < 16; ++kk2) {
            float4 b = *(float4*)&Bs[kk2][tc];
            float4 a0 = *(float4*)&As[kk2][tr];
            float4 a1 = *(float4*)&As[kk2][tr + 4];
            float a[8] = {a0.x, a0.y, a0.z, a0.w, a1.x, a1.y, a1.z, a1.w};
#pragma unroll
            for (int r = 0; r < 8; ++r) {
                acc[r][0] += a[r] * b.x;
                acc[r][1] += a[r] * b.y;
                acc[r][2] += a[r] * b.z;
                acc[r][3] += a[r] * b.w;
            }
        }
        __syncthreads();
    }
#pragma unroll
    for (int r = 0; r < 8; ++r) {
        int gr = row0 + tr + r;
        if (gr < n) {
            float4 o = make_float4(acc[r][0], acc[r][1], acc[r][2], acc[r][3]);
            if (bias) {
                o.x += bias[tc + 0];
                o.y += bias[tc + 1];
                o.z += bias[tc + 2];
                o.w += bias[tc + 3];
            }
            *(float4*)(C + (size_t)gr * HD + tc) = o;
        }
    }
}

// ---------------- fused aggregate: out[v] = relu( sum_{e:dst=v} xm[src]
//   + segE[v]@We + deg[v]*(bm+be) + selfadd[v] ) ----------------
// 32 lanes x float4 per node, 8 nodes per block, edge loop unrolled x4 (MLP)

__global__ __launch_bounds__(256) void agg_kernel(
    const int* __restrict__ row_ptr, const int* __restrict__ csr_s,
    const float* __restrict__ xm, const float* __restrict__ selfadd,
    const float* __restrict__ segE, const float* __restrict__ We,
    const float* __restrict__ bm, const float* __restrict__ be,
    const float* __restrict__ degf, float* __restrict__ out, int n) {
    __shared__ float WeS[FE * HD];
    int tid = threadIdx.x;
    for (int i = tid; i < FE * HD; i += 256) WeS[i] = We[i];
    __syncthreads();
    int node = blockIdx.x * 8 + (tid >> 5);
    if (node >= n) return;
    int c4 = (tid & 31) * 4;
    int beg = row_ptr[node], end = row_ptr[node + 1];
    float4 a0 = make_float4(0.f, 0.f, 0.f, 0.f);
    float4 a1 = a0, a2 = a0, a3 = a0;
    int j = beg;
    for (; j + 3 < end; j += 4) {
        int u0 = csr_s[j], u1 = csr_s[j + 1], u2 = csr_s[j + 2], u3 = csr_s[j + 3];
        float4 v0 = *(const float4*)(xm + (size_t)u0 * HD + c4);
        float4 v1 = *(const float4*)(xm + (size_t)u1 * HD + c4);
        float4 v2 = *(const float4*)(xm + (size_t)u2 * HD + c4);
        float4 v3 = *(const float4*)(xm + (size_t)u3 * HD + c4);
        a0.x += v0.x; a0.y += v0.y; a0.z += v0.z; a0.w += v0.w;
        a1.x += v1.x; a1.y += v1.y; a1.z += v1.z; a1.w += v1.w;
        a2.x += v2.x; a2.y += v2.y; a2.z += v2.z; a2.w += v2.w;
        a3.x += v3.x; a3.y += v3.y; a3.z += v3.z; a3.w += v3.w;
    }
    for (; j < end; ++j) {
        int u = csr_s[j];
        float4 v = *(const float4*)(xm + (size_t)u * HD + c4);
        a0.x += v.x; a0.y += v.y; a0.z += v.z; a0.w += v.w;
    }
    float4 s;
    s.x = (a0.x + a1.x) + (a2.x + a3.x);
    s.y = (a0.y + a1.y) + (a2.y + a3.y);
    s.z = (a0.z + a1.z) + (a2.z + a3.z);
    s.w = (a0.w + a1.w) + (a2.w + a3.w);

    float dg = degf[node];
    float4 bmv = *(const float4*)(bm + c4);
    float4 bev = *(const float4*)(be + c4);
    float4 et;
    et.x = dg * (bmv.x + bev.x);
    et.y = dg * (bmv.y + bev.y);
    et.z = dg * (bmv.z + bev.z);
    et.w = dg * (bmv.w + bev.w);
    const float* se = segE + (size_t)node * FE;
#pragma unroll
    for (int k = 0; k < FE; ++k) {
        float w = se[k];
        float4 wv = *(float4*)&WeS[k * HD + c4];
        et.x += w * wv.x; et.y += w * wv.y; et.z += w * wv.z; et.w += w * wv.w;
    }
    float4 sa = *(const float4*)(selfadd + (size_t)node * HD + c4);
    float4 r;
    r.x = fmaxf(s.x + et.x + sa.x, 0.f);
    r.y = fmaxf(s.y + et.y + sa.y, 0.f);
    r.z = fmaxf(s.z + et.z + sa.z, 0.f);
    r.w = fmaxf(s.w + et.w + sa.w, 0.f);
    *(float4*)(out + (size_t)node * HD + c4) = r;
}

// ---------------- mean pool (batch sorted): 4 partial blocks per graph ----------------

__global__ void pool_partial(const float* __restrict__ h, const int* __restrict__ batch,
                             float* __restrict__ pooled4) {
    int g = blockIdx.x;
    int q = blockIdx.y;
    int f = threadIdx.x;
    int lo = 0, hi = NN;
    while (lo < hi) { int m = (lo + hi) >> 1; if (batch[m] < g) lo = m + 1; else hi = m; }
    int s = lo;
    lo = s; hi = NN;
    while (lo < hi) { int m = (lo + hi) >> 1; if (batch[m] < g + 1) lo = m + 1; else hi = m; }
    int e = lo;
    int len = e - s;
    int c0 = s + (len * q) / 4;
    int c1 = s + (len * (q + 1)) / 4;
    float acc = 0.f;
    for (int v = c0; v < c1; ++v) acc += h[(size_t)v * HD + f];
    pooled4[((size_t)q * NG + g) * HD + f] = acc;
}

// ---------------- fusion head ----------------

__global__ void head_kernel(const float* __restrict__ pooled4, const int* __restrict__ batch,
                            const float* __restrict__ lf, const float* __restrict__ pfe,
                            const float* __restrict__ Wl, const float* __restrict__ bl,
                            const float* __restrict__ Wp, const float* __restrict__ bp,
                            const float* __restrict__ Wf, const float* __restrict__ bfv,
                            const float* __restrict__ Wo, const float* __restrict__ bo,
                            float* __restrict__ out) {
    __shared__ float cat[3 * HD];
    __shared__ float red[HD];
    int g = blockIdx.x, j = threadIdx.x;
    int lo = 0, hi = NN;
    while (lo < hi) { int m = (lo + hi) >> 1; if (batch[m] < g) lo = m + 1; else hi = m; }
    int s0 = lo;
    lo = s0; hi = NN;
    while (lo < hi) { int m = (lo + hi) >> 1; if (batch[m] < g + 1) lo = m + 1; else hi = m; }
    float cntf = (float)(lo - s0);
    float p = pooled4[(size_t)g * HD + j] + pooled4[((size_t)NG + g) * HD + j] +
              pooled4[((size_t)2 * NG + g) * HD + j] + pooled4[((size_t)3 * NG + g) * HD + j];
    cat[j] = p / fmaxf(cntf, 1.f);
    float s = bl[j];
    for (int k = 0; k < FL; ++k) s += lf[g * FL + k] * Wl[k * HD + j];
    cat[HD + j] = s;
    s = bp[j];
    for (int k = 0; k < FPOC; ++k) s += pfe[g * FPOC + k] * Wp[k * HD + j];
    cat[2 * HD + j] = s;
    __syncthreads();
    float fj = bfv[j];
    for (int k = 0; k < 3 * HD; ++k) fj += cat[k] * Wf[k * HD + j];
    red[j] = fj * Wo[j];
    __syncthreads();
    for (int off = 64; off > 0; off >>= 1) {
        if (j < off) red[j] += red[j + off];
        __syncthreads();
    }
    if (j == 0) out[g] = red[0] + bo[0];
}

// ---------------- launch ----------------

extern "C" void kernel_launch(void* const* d_in, const int* in_sizes, int n_in,
                              void* d_out, int out_size, void* d_ws, size_t ws_size,
                              hipStream_t stream) {
    const float* x       = (const float*)d_in[0];
    const int*   ei      = (const int*)d_in[1];
    const float* ea      = (const float*)d_in[2];
    const int*   batch   = (const int*)d_in[3];
    const float* lf      = (const float*)d_in[4];
    const float* pfe     = (const float*)d_in[5];
    const float* W1_msg  = (const float*)d_in[6];
    const float* b1_msg  = (const float*)d_in[7];
    const float* W1_edge = (const float*)d_in[8];
    const float* b1_edge = (const float*)d_in[9];
    const float* W1_self = (const float*)d_in[10];
    const float* b1_self = (const float*)d_in[11];
    const float* Wk_msg  = (const float*)d_in[12];
    const float* bk_msg  = (const float*)d_in[13];
    const float* Wk_edge = (const float*)d_in[14];
    const float* bk_edge = (const float*)d_in[15];
    const float* Wl      = (const float*)d_in[16];
    const float* bl      = (const float*)d_in[17];
    const float* Wp      = (const float*)d_in[18];
    const float* bp      = (const float*)d_in[19];
    const float* Wf      = (const float*)d_in[20];
    const float* bfv     = (const float*)d_in[21];
    const float* Wo      = (const float*)d_in[22];
    const float* bo      = (const float*)d_in[23];

    char* wsp = (char*)d_ws;
    size_t off = 0;
    auto carve = [&](size_t bytes) -> void* {
        char* p = wsp + off;
        off += (bytes + 255) & ~(size_t)255;
        return (void*)p;
    };
    int*   cnt     = (int*)carve((size_t)NN * 4);
    int*   row_ptr = (int*)carve((size_t)(NN + 1) * 4);
    int*   fillc   = (int*)carve((size_t)NN * 4);
    float* degf    = (float*)carve((size_t)NN * 4);
    int*   csr_s   = (int*)carve((size_t)NE * 4);
    int*   csr_e   = (int*)carve((size_t)NE * 4);
    float* segE    = (float*)carve((size_t)NN * FE * 4);
    float* bufA    = (float*)carve((size_t)NN * HD * 4);
    float* bufB    = (float*)carve((size_t)NN * HD * 4);
    float* bufC    = (float*)carve((size_t)NN * HD * 4);
    float* pooled4 = (float*)carve((size_t)4 * NG * HD * 4);
    int*   bsum    = (int*)carve((size_t)256 * 4);
    int*   bpre    = (int*)carve((size_t)256 * 4);

    const int NBLK = (NN + 255) / 256;  // 196

    hipMemsetAsync(cnt, 0, (size_t)NN * 4, stream);
    hipMemsetAsync(fillc, 0, (size_t)NN * 4, stream);

    count_kernel<<<(NE + 255) / 256, 256, 0, stream>>>(ei, cnt);
    bsum_kernel<<<NBLK, 256, 0, stream>>>(cnt, bsum);
    bscan_kernel<<<1, 256, 0, stream>>>(bsum, bpre, NBLK);
    rowptr_kernel<<<NBLK, 256, 0, stream>>>(cnt, bpre, row_ptr, degf);
    fill_kernel<<<(NE + 255) / 256, 256, 0, stream>>>(ei, row_ptr, fillc, csr_s, csr_e);
    sege_kernel<<<(NN + 15) / 16, 256, 0, stream>>>(row_ptr, csr_e, ea, segE);

    dim3 ggrid((NN + 63) / 64);
    gemm128<<<ggrid, 256, 0, stream>>>(x, W1_msg, nullptr, bufC, NN, FN);
    gemm128<<<ggrid, 256, 0, stream>>>(x, W1_self, b1_self, bufB, NN, FN);
    agg_kernel<<<(NN + 7) / 8, 256, 0, stream>>>(row_ptr, csr_s, bufC, bufB, segE, W1_edge,
                                                 b1_msg, b1_edge, degf, bufA, NN);

    float* hcur = bufA;
    float* hnext = bufB;
    for (int i = 0; i < NSTACK; ++i) {
        gemm128<<<ggrid, 256, 0, stream>>>(hcur, Wk_msg + (size_t)i * HD * HD, nullptr, bufC,
                                           NN, HD);
        agg_kernel<<<(NN + 7) / 8, 256, 0, stream>>>(row_ptr, csr_s, bufC, hcur, segE,
                                                     Wk_edge + (size_t)i * FE * HD,
                                                     bk_msg + i * HD, bk_edge + i * HD, degf,
                                                     hnext, NN);
        float* t = hcur; hcur = hnext; hnext = t;
    }

    pool_partial<<<dim3(NG, 4), HD, 0, stream>>>(hcur, batch, pooled4);
    head_kernel<<<NG, HD, 0, stream>>>(pooled4, batch, lf, pfe, Wl, bl, Wp, bp, Wf, bfv,
                                       Wo, bo, (float*)d_out);
}

// Round 3
// 588.072 us; speedup vs baseline: 1.9314x; 1.0952x over previous
//
#include <hip/hip_runtime.h>
#include <cstdint>

#define NN 50000
#define NE 640000
#define NG 128
#define HD 128
#define FN 64
#define FE 16
#define FL 200
#define FPOC 100
#define NSTACK 3

typedef unsigned short ushort_t;
typedef short short8 __attribute__((ext_vector_type(8)));
typedef float f32x4 __attribute__((ext_vector_type(4)));

__device__ __forceinline__ ushort_t f2bf(float f) {
    unsigned u = __float_as_uint(f);
    unsigned r = (u + 0x7fffu + ((u >> 16) & 1u)) >> 16;
    return (ushort_t)r;
}
__device__ __forceinline__ float bf2f(ushort_t u) {
    return __uint_as_float(((unsigned)u) << 16);
}

// ---------------- CSR build ----------------

__global__ void count_kernel(const int* __restrict__ ei, int* __restrict__ cnt) {
    int e = blockIdx.x * 256 + threadIdx.x;
    if (e < NE) atomicAdd(&cnt[ei[NE + e]], 1);
}

__global__ void bsum_kernel(const int* __restrict__ cnt, int* __restrict__ bsum) {
    __shared__ int s[256];
    int t = threadIdx.x;
    int i = blockIdx.x * 256 + t;
    int v = (i < NN) ? cnt[i] : 0;
    s[t] = v;
    __syncthreads();
    for (int off = 128; off > 0; off >>= 1) {
        if (t < off) s[t] += s[t + off];
        __syncthreads();
    }
    if (t == 0) bsum[blockIdx.x] = s[0];
}

__global__ void bscan_kernel(const int* __restrict__ bsum, int* __restrict__ bpre, int nb) {
    __shared__ int s[256];
    int t = threadIdx.x;
    int v = (t < nb) ? bsum[t] : 0;
    s[t] = v;
    __syncthreads();
    for (int off = 1; off < 256; off <<= 1) {
        int w = (t >= off) ? s[t - off] : 0;
        __syncthreads();
        s[t] += w;
        __syncthreads();
    }
    if (t < nb) bpre[t] = s[t] - v;
}

__global__ void rowptr_kernel(const int* __restrict__ cnt, const int* __restrict__ bpre,
                              int* __restrict__ row_ptr, float* __restrict__ degf) {
    __shared__ int s[256];
    int t = threadIdx.x;
    int i = blockIdx.x * 256 + t;
    int v = (i < NN) ? cnt[i] : 0;
    s[t] = v;
    __syncthreads();
    for (int off = 1; off < 256; off <<= 1) {
        int w = (t >= off) ? s[t - off] : 0;
        __syncthreads();
        s[t] += w;
        __syncthreads();
    }
    if (i < NN) {
        row_ptr[i] = s[t] - v + bpre[blockIdx.x];
        degf[i] = (float)v;
    }
    if (i == 0) row_ptr[NN] = NE;
}

__global__ void fill_kernel(const int* __restrict__ ei, const int* __restrict__ row_ptr,
                            int* __restrict__ fill, int* __restrict__ csr_s,
                            int* __restrict__ csr_e) {
    int e = blockIdx.x * 256 + threadIdx.x;
    if (e < NE) {
        int s = ei[e];
        int d = ei[NE + e];
        int p = row_ptr[d] + atomicAdd(&fill[d], 1);
        csr_s[p] = s;
        csr_e[p] = e;
    }
}

__global__ __launch_bounds__(256) void sege_kernel(
    const int* __restrict__ row_ptr, const int* __restrict__ csr_e,
    const float* __restrict__ ea, float* __restrict__ segE) {
    int node = blockIdx.x * 16 + (threadIdx.x >> 4);
    int f = threadIdx.x & 15;
    if (node >= NN) return;
    int beg = row_ptr[node], end = row_ptr[node + 1];
    float a0 = 0.f, a1 = 0.f;
    int j = beg;
    for (; j + 1 < end; j += 2) {
        int e0 = csr_e[j], e1 = csr_e[j + 1];
        a0 += ea[(size_t)e0 * FE + f];
        a1 += ea[(size_t)e1 * FE + f];
    }
    if (j < end) a0 += ea[(size_t)csr_e[j] * FE + f];
    segE[node * FE + f] = a0 + a1;
}

// ---------------- fp32 -> bf16 cast for x ----------------

__global__ void cast_x_kernel(const float* __restrict__ x, ushort_t* __restrict__ xb) {
    int t = blockIdx.x * 256 + threadIdx.x;
    int base = t * 8;
    if (base >= NN * FN) return;
    float4 a = *(const float4*)(x + base);
    float4 b = *(const float4*)(x + base + 4);
    ushort_t o[8];
    o[0] = f2bf(a.x); o[1] = f2bf(a.y); o[2] = f2bf(a.z); o[3] = f2bf(a.w);
    o[4] = f2bf(b.x); o[5] = f2bf(b.y); o[6] = f2bf(b.z); o[7] = f2bf(b.w);
    *(uint4*)(xb + base) = *(uint4*)o;
}

// ---------------- weight repack into MFMA B-fragment order ----------------
// B-frag for 16x16x32: lane holds B[k=ks*32+quad*8+j][n=nt*16+(lane&15)], j=0..7
// pack element offset: ((nt*KS + ks)*64 + lane)*8 + j

__global__ void repack_kernel(const float* __restrict__ W1_msg,
                              const float* __restrict__ W1_self,
                              const float* __restrict__ Wk_msg,
                              ushort_t* __restrict__ pack) {
    int mid = blockIdx.y;
    const float* src;
    int K;
    size_t doff;
    if (mid == 0)      { src = W1_msg;  K = 64;  doff = 0; }
    else if (mid == 1) { src = W1_self; K = 64;  doff = 8192; }
    else               { src = Wk_msg + (size_t)(mid - 2) * HD * HD; K = 128;
                         doff = 16384 + (size_t)(mid - 2) * 16384; }
    int KS = K / 32;
    int t = blockIdx.x * 256 + threadIdx.x;
    if (t >= 8 * KS * 64) return;
    int lane = t & 63;
    int nk = t >> 6;
    int ks = nk % KS, nt = nk / KS;
    int n = nt * 16 + (lane & 15);
    int kb = ks * 32 + (lane >> 4) * 8;
    ushort_t o[8];
#pragma unroll
    for (int j = 0; j < 8; ++j) o[j] = f2bf(src[(size_t)(kb + j) * HD + n]);
    *(uint4*)(pack + doff + (size_t)t * 8) = *(uint4*)o;
}

// ---------------- MFMA GEMM: C[n,128] = A[n,K](bf16) @ Wpack, bf16 out ----------------

template <int K>
__global__ __launch_bounds__(256) void gemm_mfma(const ushort_t* __restrict__ A,
                                                 const ushort_t* __restrict__ Bp,
                                                 ushort_t* __restrict__ C, int n) {
    constexpr int KS = K / 32;
    constexpr int STR = K + 8;
    __shared__ __align__(16) ushort_t As[64 * STR];
    int tid = threadIdx.x;
    int row0 = blockIdx.x * 64;
    constexpr int CH = K / 8;             // 16B chunks per row
    constexpr int PASS = 64 * CH / 256;
#pragma unroll
    for (int p = 0; p < PASS; ++p) {
        int c = p * 256 + tid;
        int r = c / CH, col = c % CH;
        int gr = row0 + r;
        uint4 v = make_uint4(0u, 0u, 0u, 0u);
        if (gr < n) v = *(const uint4*)(A + (size_t)gr * K + col * 8);
        *(uint4*)(&As[r * STR + col * 8]) = v;
    }
    __syncthreads();
    int lane = tid & 63, wave = tid >> 6;
    int m = lane & 15, quad = lane >> 4;
    f32x4 acc[8];
#pragma unroll
    for (int i = 0; i < 8; ++i) acc[i] = (f32x4)(0.f);
    const short8* Bv = (const short8*)Bp;
#pragma unroll
    for (int ks = 0; ks < KS; ++ks) {
        short8 a = *(const short8*)(&As[(wave * 16 + m) * STR + ks * 32 + quad * 8]);
#pragma unroll
        for (int nt = 0; nt < 8; ++nt) {
            short8 b = Bv[(nt * KS + ks) * 64 + lane];
            acc[nt] = __builtin_amdgcn_mfma_f32_16x16x32_bf16(a, b, acc[nt], 0, 0, 0);
        }
    }
    // C/D layout: col = lane&15, row = quad*4 + reg
#pragma unroll
    for (int nt = 0; nt < 8; ++nt) {
#pragma unroll
        for (int r = 0; r < 4; ++r) {
            int grow = row0 + wave * 16 + quad * 4 + r;
            if (grow < n) C[(size_t)grow * HD + nt * 16 + m] = f2bf(acc[nt][r]);
        }
    }
}

// ---------------- fused aggregate (bf16 payload, fp32 accumulate) ----------------
// out[v] = relu( sum_{e:dst=v} xm[src] + segE[v]@We + deg[v]*(bm+be) + self[v] (+sb) )

__device__ __forceinline__ void accum8(float* acc, uint4 v) {
    unsigned d0 = v.x, d1 = v.y, d2 = v.z, d3 = v.w;
    acc[0] += __uint_as_float(d0 << 16);
    acc[1] += __uint_as_float(d0 & 0xffff0000u);
    acc[2] += __uint_as_float(d1 << 16);
    acc[3] += __uint_as_float(d1 & 0xffff0000u);
    acc[4] += __uint_as_float(d2 << 16);
    acc[5] += __uint_as_float(d2 & 0xffff0000u);
    acc[6] += __uint_as_float(d3 << 16);
    acc[7] += __uint_as_float(d3 & 0xffff0000u);
}

__global__ __launch_bounds__(256) void agg_kernel(
    const int* __restrict__ row_ptr, const int* __restrict__ csr_s,
    const ushort_t* __restrict__ xm, const ushort_t* __restrict__ selfb,
    const float* __restrict__ segE, const float* __restrict__ We,
    const float* __restrict__ bm, const float* __restrict__ be,
    const float* __restrict__ sb, const float* __restrict__ degf,
    ushort_t* __restrict__ out, int n) {
    __shared__ float WeS[FE * HD];
    int tid = threadIdx.x;
    for (int i = tid; i < FE * HD; i += 256) WeS[i] = We[i];
    __syncthreads();
    int node = blockIdx.x * 16 + (tid >> 4);
    if (node >= n) return;
    int c8 = (tid & 15) * 8;
    int beg = row_ptr[node], end = row_ptr[node + 1];
    float a0[8] = {0.f, 0.f, 0.f, 0.f, 0.f, 0.f, 0.f, 0.f};
    float a1[8] = {0.f, 0.f, 0.f, 0.f, 0.f, 0.f, 0.f, 0.f};
    float a2[8] = {0.f, 0.f, 0.f, 0.f, 0.f, 0.f, 0.f, 0.f};
    float a3[8] = {0.f, 0.f, 0.f, 0.f, 0.f, 0.f, 0.f, 0.f};
    int j = beg;
    for (; j + 3 < end; j += 4) {
        int u0 = csr_s[j], u1 = csr_s[j + 1], u2 = csr_s[j + 2], u3 = csr_s[j + 3];
        uint4 v0 = *(const uint4*)(xm + (size_t)u0 * HD + c8);
        uint4 v1 = *(const uint4*)(xm + (size_t)u1 * HD + c8);
        uint4 v2 = *(const uint4*)(xm + (size_t)u2 * HD + c8);
        uint4 v3 = *(const uint4*)(xm + (size_t)u3 * HD + c8);
        accum8(a0, v0);
        accum8(a1, v1);
        accum8(a2, v2);
        accum8(a3, v3);
    }
    for (; j < end; ++j) {
        int u = csr_s[j];
        uint4 v = *(const uint4*)(xm + (size_t)u * HD + c8);
        accum8(a0, v);
    }
    float dg = degf[node];
    const float* se = segE + (size_t)node * FE;
    float et[8];
#pragma unroll
    for (int i = 0; i < 8; ++i) et[i] = dg * (bm[c8 + i] + be[c8 + i]);
#pragma unroll
    for (int k = 0; k < FE; ++k) {
        float w = se[k];
#pragma unroll
        for (int i = 0; i < 8; ++i) et[i] += w * WeS[k * HD + c8 + i];
    }
    float sf[8];
    {
        uint4 sv = *(const uint4*)(selfb + (size_t)node * HD + c8);
        unsigned d0 = sv.x, d1 = sv.y, d2 = sv.z, d3 = sv.w;
        sf[0] = __uint_as_float(d0 << 16);
        sf[1] = __uint_as_float(d0 & 0xffff0000u);
        sf[2] = __uint_as_float(d1 << 16);
        sf[3] = __uint_as_float(d1 & 0xffff0000u);
        sf[4] = __uint_as_float(d2 << 16);
        sf[5] = __uint_as_float(d2 & 0xffff0000u);
        sf[6] = __uint_as_float(d3 << 16);
        sf[7] = __uint_as_float(d3 & 0xffff0000u);
    }
    ushort_t o[8];
#pragma unroll
    for (int i = 0; i < 8; ++i) {
        float r = (a0[i] + a1[i]) + (a2[i] + a3[i]) + et[i] + sf[i];
        if (sb) r += sb[c8 + i];
        o[i] = f2bf(fmaxf(r, 0.f));
    }
    *(uint4*)(out + (size_t)node * HD + c8) = *(uint4*)o;
}

// ---------------- mean pool (batch sorted): 4 partial blocks per graph ----------------

__global__ void pool_partial(const ushort_t* __restrict__ h, const int* __restrict__ batch,
                             float* __restrict__ pooled4) {
    int g = blockIdx.x;
    int q = blockIdx.y;
    int f = threadIdx.x;
    int lo = 0, hi = NN;
    while (lo < hi) { int m = (lo + hi) >> 1; if (batch[m] < g) lo = m + 1; else hi = m; }
    int s = lo;
    lo = s; hi = NN;
    while (lo < hi) { int m = (lo + hi) >> 1; if (batch[m] < g + 1) lo = m + 1; else hi = m; }
    int e = lo;
    int len = e - s;
    int c0 = s + (len * q) / 4;
    int c1 = s + (len * (q + 1)) / 4;
    float acc = 0.f;
    for (int v = c0; v < c1; ++v) acc += bf2f(h[(size_t)v * HD + f]);
    pooled4[((size_t)q * NG + g) * HD + f] = acc;
}

// ---------------- fusion head ----------------

__global__ void head_kernel(const float* __restrict__ pooled4, const int* __restrict__ batch,
                            const float* __restrict__ lf, const float* __restrict__ pfe,
                            const float* __restrict__ Wl, const float* __restrict__ bl,
                            const float* __restrict__ Wp, const float* __restrict__ bp,
                            const float* __restrict__ Wf, const float* __restrict__ bfv,
                            const float* __restrict__ Wo, const float* __restrict__ bo,
                            float* __restrict__ out) {
    __shared__ float cat[3 * HD];
    __shared__ float red[HD];
    int g = blockIdx.x, j = threadIdx.x;
    int lo = 0, hi = NN;
    while (lo < hi) { int m = (lo + hi) >> 1; if (batch[m] < g) lo = m + 1; else hi = m; }
    int s0 = lo;
    lo = s0; hi = NN;
    while (lo < hi) { int m = (lo + hi) >> 1; if (batch[m] < g + 1) lo = m + 1; else hi = m; }
    float cntf = (float)(lo - s0);
    float p = pooled4[(size_t)g * HD + j] + pooled4[((size_t)NG + g) * HD + j] +
              pooled4[((size_t)2 * NG + g) * HD + j] + pooled4[((size_t)3 * NG + g) * HD + j];
    cat[j] = p / fmaxf(cntf, 1.f);
    float s = bl[j];
    for (int k = 0; k < FL; ++k) s += lf[g * FL + k] * Wl[k * HD + j];
    cat[HD + j] = s;
    s = bp[j];
    for (int k = 0; k < FPOC; ++k) s += pfe[g * FPOC + k] * Wp[k * HD + j];
    cat[2 * HD + j] = s;
    __syncthreads();
    float fj = bfv[j];
    for (int k = 0; k < 3 * HD; ++k) fj += cat[k] * Wf[k * HD + j];
    red[j] = fj * Wo[j];
    __syncthreads();
    for (int off = 64; off > 0; off >>= 1) {
        if (j < off) red[j] += red[j + off];
        __syncthreads();
    }
    if (j == 0) out[g] = red[0] + bo[0];
}

// ---------------- launch ----------------

extern "C" void kernel_launch(void* const* d_in, const int* in_sizes, int n_in,
                              void* d_out, int out_size, void* d_ws, size_t ws_size,
                              hipStream_t stream) {
    const float* x       = (const float*)d_in[0];
    const int*   ei      = (const int*)d_in[1];
    const float* ea      = (const float*)d_in[2];
    const int*   batch   = (const int*)d_in[3];
    const float* lf      = (const float*)d_in[4];
    const float* pfe     = (const float*)d_in[5];
    const float* W1_msg  = (const float*)d_in[6];
    const float* b1_msg  = (const float*)d_in[7];
    const float* W1_edge = (const float*)d_in[8];
    const float* b1_edge = (const float*)d_in[9];
    const float* W1_self = (const float*)d_in[10];
    const float* b1_self = (const float*)d_in[11];
    const float* Wk_msg  = (const float*)d_in[12];
    const float* bk_msg  = (const float*)d_in[13];
    const float* Wk_edge = (const float*)d_in[14];
    const float* bk_edge = (const float*)d_in[15];
    const float* Wl      = (const float*)d_in[16];
    const float* bl      = (const float*)d_in[17];
    const float* Wp      = (const float*)d_in[18];
    const float* bp      = (const float*)d_in[19];
    const float* Wf      = (const float*)d_in[20];
    const float* bfv     = (const float*)d_in[21];
    const float* Wo      = (const float*)d_in[22];
    const float* bo      = (const float*)d_in[23];

    char* wsp = (char*)d_ws;
    size_t off = 0;
    auto carve = [&](size_t bytes) -> void* {
        char* p = wsp + off;
        off += (bytes + 255) & ~(size_t)255;
        return (void*)p;
    };
    int*      cnt     = (int*)carve((size_t)NN * 4);
    int*      row_ptr = (int*)carve((size_t)(NN + 1) * 4);
    int*      fillc   = (int*)carve((size_t)NN * 4);
    float*    degf    = (float*)carve((size_t)NN * 4);
    int*      csr_s   = (int*)carve((size_t)NE * 4);
    int*      csr_e   = (int*)carve((size_t)NE * 4);
    float*    segE    = (float*)carve((size_t)NN * FE * 4);
    ushort_t* xb      = (ushort_t*)carve((size_t)NN * FN * 2);
    ushort_t* pack    = (ushort_t*)carve((size_t)65536 * 2);
    ushort_t* bufA    = (ushort_t*)carve((size_t)NN * HD * 2);
    ushort_t* bufB    = (ushort_t*)carve((size_t)NN * HD * 2);
    ushort_t* bufC    = (ushort_t*)carve((size_t)NN * HD * 2);
    float*    pooled4 = (float*)carve((size_t)4 * NG * HD * 4);
    int*      bsum    = (int*)carve((size_t)256 * 4);
    int*      bpre    = (int*)carve((size_t)256 * 4);

    const int NBLK = (NN + 255) / 256;

    hipMemsetAsync(cnt, 0, (size_t)NN * 4, stream);
    hipMemsetAsync(fillc, 0, (size_t)NN * 4, stream);

    count_kernel<<<(NE + 255) / 256, 256, 0, stream>>>(ei, cnt);
    bsum_kernel<<<NBLK, 256, 0, stream>>>(cnt, bsum);
    bscan_kernel<<<1, 256, 0, stream>>>(bsum, bpre, NBLK);
    rowptr_kernel<<<NBLK, 256, 0, stream>>>(cnt, bpre, row_ptr, degf);
    fill_kernel<<<(NE + 255) / 256, 256, 0, stream>>>(ei, row_ptr, fillc, csr_s, csr_e);
    sege_kernel<<<(NN + 15) / 16, 256, 0, stream>>>(row_ptr, csr_e, ea, segE);
    cast_x_kernel<<<(NN * FN / 8 + 255) / 256, 256, 0, stream>>>(x, xb);
    repack_kernel<<<dim3(8, 5), 256, 0, stream>>>(W1_msg, W1_self, Wk_msg, pack);

    dim3 ggrid((NN + 63) / 64);
    // conv1
    gemm_mfma<64><<<ggrid, 256, 0, stream>>>(xb, pack, bufC, NN);            // msg
    gemm_mfma<64><<<ggrid, 256, 0, stream>>>(xb, pack + 8192, bufB, NN);     // self
    agg_kernel<<<(NN + 15) / 16, 256, 0, stream>>>(row_ptr, csr_s, bufC, bufB, segE,
                                                   W1_edge, b1_msg, b1_edge, b1_self,
                                                   degf, bufA, NN);
    // stacked convs
    ushort_t* hcur = bufA;
    ushort_t* hnext = bufB;
    for (int i = 0; i < NSTACK; ++i) {
        gemm_mfma<128><<<ggrid, 256, 0, stream>>>(hcur, pack + 16384 + (size_t)i * 16384,
                                                  bufC, NN);
        agg_kernel<<<(NN + 15) / 16, 256, 0, stream>>>(row_ptr, csr_s, bufC, hcur, segE,
                                                       Wk_edge + (size_t)i * FE * HD,
                                                       bk_msg + i * HD, bk_edge + i * HD,
                                                       nullptr, degf, hnext, NN);
        ushort_t* t = hcur; hcur = hnext; hnext = t;
    }

    pool_partial<<<dim3(NG, 4), HD, 0, stream>>>(hcur, batch, pooled4);
    head_kernel<<<NG, HD, 0, stream>>>(pooled4, batch, lf, pfe, Wl, bl, Wp, bp, Wf, bfv,
                                       Wo, bo, (float*)d_out);
}

// Round 4
// 576.514 us; speedup vs baseline: 1.9701x; 1.0200x over previous
//
#include <hip/hip_runtime.h>
#include <cstdint>

#define NN 50000
#define NE 640000
#define NG 128
#define HD 128
#define FN 64
#define FE 16
#define FL 200
#define FPOC 100
#define NSTACK 3

typedef unsigned short ushort_t;
typedef short short8 __attribute__((ext_vector_type(8)));
typedef float f32x4 __attribute__((ext_vector_type(4)));

__device__ __forceinline__ ushort_t f2bf(float f) {
    unsigned u = __float_as_uint(f);
    unsigned r = (u + 0x7fffu + ((u >> 16) & 1u)) >> 16;
    return (ushort_t)r;
}
__device__ __forceinline__ float bf2f(ushort_t u) {
    return __uint_as_float(((unsigned)u) << 16);
}

// ---------------- CSR build ----------------

__global__ void count_kernel(const int* __restrict__ ei, int* __restrict__ cnt) {
    int e = blockIdx.x * 256 + threadIdx.x;
    if (e < NE) atomicAdd(&cnt[ei[NE + e]], 1);
}

__global__ void bsum_kernel(const int* __restrict__ cnt, int* __restrict__ bsum) {
    __shared__ int s[256];
    int t = threadIdx.x;
    int i = blockIdx.x * 256 + t;
    int v = (i < NN) ? cnt[i] : 0;
    s[t] = v;
    __syncthreads();
    for (int off = 128; off > 0; off >>= 1) {
        if (t < off) s[t] += s[t + off];
        __syncthreads();
    }
    if (t == 0) bsum[blockIdx.x] = s[0];
}

__global__ void bscan_kernel(const int* __restrict__ bsum, int* __restrict__ bpre, int nb) {
    __shared__ int s[256];
    int t = threadIdx.x;
    int v = (t < nb) ? bsum[t] : 0;
    s[t] = v;
    __syncthreads();
    for (int off = 1; off < 256; off <<= 1) {
        int w = (t >= off) ? s[t - off] : 0;
        __syncthreads();
        s[t] += w;
        __syncthreads();
    }
    if (t < nb) bpre[t] = s[t] - v;
}

__global__ void rowptr_kernel(const int* __restrict__ cnt, const int* __restrict__ bpre,
                              int* __restrict__ row_ptr, float* __restrict__ degf) {
    __shared__ int s[256];
    int t = threadIdx.x;
    int i = blockIdx.x * 256 + t;
    int v = (i < NN) ? cnt[i] : 0;
    s[t] = v;
    __syncthreads();
    for (int off = 1; off < 256; off <<= 1) {
        int w = (t >= off) ? s[t - off] : 0;
        __syncthreads();
        s[t] += w;
        __syncthreads();
    }
    if (i < NN) {
        row_ptr[i] = s[t] - v + bpre[blockIdx.x];
        degf[i] = (float)v;
    }
    if (i == 0) row_ptr[NN] = NE;
}

__global__ void fill_kernel(const int* __restrict__ ei, const int* __restrict__ row_ptr,
                            int* __restrict__ fill, int* __restrict__ csr_s,
                            int* __restrict__ csr_e) {
    int e = blockIdx.x * 256 + threadIdx.x;
    if (e < NE) {
        int s = ei[e];
        int d = ei[NE + e];
        int p = row_ptr[d] + atomicAdd(&fill[d], 1);
        csr_s[p] = s;
        csr_e[p] = e;
    }
}

__global__ __launch_bounds__(256) void sege_kernel(
    const int* __restrict__ row_ptr, const int* __restrict__ csr_e,
    const float* __restrict__ ea, float* __restrict__ segE) {
    int node = blockIdx.x * 16 + (threadIdx.x >> 4);
    int f = threadIdx.x & 15;
    if (node >= NN) return;
    int beg = row_ptr[node], end = row_ptr[node + 1];
    float a0 = 0.f, a1 = 0.f;
    int j = beg;
    for (; j + 1 < end; j += 2) {
        int e0 = csr_e[j], e1 = csr_e[j + 1];
        a0 += ea[(size_t)e0 * FE + f];
        a1 += ea[(size_t)e1 * FE + f];
    }
    if (j < end) a0 += ea[(size_t)csr_e[j] * FE + f];
    segE[node * FE + f] = a0 + a1;
}

// ---------------- fp32 -> bf16 cast for x ----------------

__global__ void cast_x_kernel(const float* __restrict__ x, ushort_t* __restrict__ xb) {
    int t = blockIdx.x * 256 + threadIdx.x;
    int base = t * 8;
    if (base >= NN * FN) return;
    float4 a = *(const float4*)(x + base);
    float4 b = *(const float4*)(x + base + 4);
    ushort_t o[8];
    o[0] = f2bf(a.x); o[1] = f2bf(a.y); o[2] = f2bf(a.z); o[3] = f2bf(a.w);
    o[4] = f2bf(b.x); o[5] = f2bf(b.y); o[6] = f2bf(b.z); o[7] = f2bf(b.w);
    *(uint4*)(xb + base) = *(uint4*)o;
}

// ---------------- weight repack into MFMA B-fragment order ----------------
// B-frag for 16x16x32: lane holds B[k=ks*32+quad*8+j][n=nt*16+(lane&15)], j=0..7
// pack element offset: ((nt*KS + ks)*64 + lane)*8 + j

__global__ void repack_kernel(const float* __restrict__ W1_msg,
                              const float* __restrict__ W1_self,
                              const float* __restrict__ Wk_msg,
                              ushort_t* __restrict__ pack) {
    int mid = blockIdx.y;
    const float* src;
    int K;
    size_t doff;
    if (mid == 0)      { src = W1_msg;  K = 64;  doff = 0; }
    else if (mid == 1) { src = W1_self; K = 64;  doff = 8192; }
    else               { src = Wk_msg + (size_t)(mid - 2) * HD * HD; K = 128;
                         doff = 16384 + (size_t)(mid - 2) * 16384; }
    int KS = K / 32;
    int t = blockIdx.x * 256 + threadIdx.x;
    if (t >= 8 * KS * 64) return;
    int lane = t & 63;
    int nk = t >> 6;
    int ks = nk % KS, nt = nk / KS;
    int n = nt * 16 + (lane & 15);
    int kb = ks * 32 + (lane >> 4) * 8;
    ushort_t o[8];
#pragma unroll
    for (int j = 0; j < 8; ++j) o[j] = f2bf(src[(size_t)(kb + j) * HD + n]);
    *(uint4*)(pack + doff + (size_t)t * 8) = *(uint4*)o;
}

// ---------------- MFMA GEMM: C[n,128] = A[n,K](bf16) @ Wpack, bf16 out ----------------

template <int K>
__global__ __launch_bounds__(256) void gemm_mfma(const ushort_t* __restrict__ A,
                                                 const ushort_t* __restrict__ Bp,
                                                 ushort_t* __restrict__ C, int n) {
    constexpr int KS = K / 32;
    constexpr int STR = K + 8;
    __shared__ __align__(16) ushort_t As[64 * STR];
    int tid = threadIdx.x;
    int row0 = blockIdx.x * 64;
    constexpr int CH = K / 8;
    constexpr int PASS = 64 * CH / 256;
#pragma unroll
    for (int p = 0; p < PASS; ++p) {
        int c = p * 256 + tid;
        int r = c / CH, col = c % CH;
        int gr = row0 + r;
        uint4 v = make_uint4(0u, 0u, 0u, 0u);
        if (gr < n) v = *(const uint4*)(A + (size_t)gr * K + col * 8);
        *(uint4*)(&As[r * STR + col * 8]) = v;
    }
    __syncthreads();
    int lane = tid & 63, wave = tid >> 6;
    int m = lane & 15, quad = lane >> 4;
    f32x4 acc[8];
#pragma unroll
    for (int i = 0; i < 8; ++i) acc[i] = (f32x4)(0.f);
    const short8* Bv = (const short8*)Bp;
#pragma unroll
    for (int ks = 0; ks < KS; ++ks) {
        short8 a = *(const short8*)(&As[(wave * 16 + m) * STR + ks * 32 + quad * 8]);
#pragma unroll
        for (int nt = 0; nt < 8; ++nt) {
            short8 b = Bv[(nt * KS + ks) * 64 + lane];
            acc[nt] = __builtin_amdgcn_mfma_f32_16x16x32_bf16(a, b, acc[nt], 0, 0, 0);
        }
    }
#pragma unroll
    for (int nt = 0; nt < 8; ++nt) {
#pragma unroll
        for (int r = 0; r < 4; ++r) {
            int grow = row0 + wave * 16 + quad * 4 + r;
            if (grow < n) C[(size_t)grow * HD + nt * 16 + m] = f2bf(acc[nt][r]);
        }
    }
}

// conv1 fused: one A-staging, 16 n-tiles (msg tiles 0..7 -> Cm, self tiles 8..15 -> Cs)
__global__ __launch_bounds__(256) void gemm_mfma_conv1(const ushort_t* __restrict__ A,
                                                       const ushort_t* __restrict__ Bp,
                                                       ushort_t* __restrict__ Cm,
                                                       ushort_t* __restrict__ Cs, int n) {
    constexpr int K = 64, KS = 2, STR = K + 8;
    __shared__ __align__(16) ushort_t As[64 * STR];
    int tid = threadIdx.x;
    int row0 = blockIdx.x * 64;
    constexpr int CH = K / 8;
    constexpr int PASS = 64 * CH / 256;
#pragma unroll
    for (int p = 0; p < PASS; ++p) {
        int c = p * 256 + tid;
        int r = c / CH, col = c % CH;
        int gr = row0 + r;
        uint4 v = make_uint4(0u, 0u, 0u, 0u);
        if (gr < n) v = *(const uint4*)(A + (size_t)gr * K + col * 8);
        *(uint4*)(&As[r * STR + col * 8]) = v;
    }
    __syncthreads();
    int lane = tid & 63, wave = tid >> 6;
    int m = lane & 15, quad = lane >> 4;
    f32x4 acc[16];
#pragma unroll
    for (int i = 0; i < 16; ++i) acc[i] = (f32x4)(0.f);
    const short8* Bv = (const short8*)Bp;
#pragma unroll
    for (int ks = 0; ks < KS; ++ks) {
        short8 a = *(const short8*)(&As[(wave * 16 + m) * STR + ks * 32 + quad * 8]);
#pragma unroll
        for (int nt = 0; nt < 16; ++nt) {
            short8 b = Bv[(nt * KS + ks) * 64 + lane];
            acc[nt] = __builtin_amdgcn_mfma_f32_16x16x32_bf16(a, b, acc[nt], 0, 0, 0);
        }
    }
#pragma unroll
    for (int nt = 0; nt < 16; ++nt) {
        ushort_t* dst = (nt < 8) ? Cm : Cs;
        int col = (nt & 7) * 16 + m;
#pragma unroll
        for (int r = 0; r < 4; ++r) {
            int grow = row0 + wave * 16 + quad * 4 + r;
            if (grow < n) dst[(size_t)grow * HD + col] = f2bf(acc[nt][r]);
        }
    }
}

// ---------------- fused aggregate (bf16 payload, fp32 accumulate) ----------------
// 32 lanes x uint2 (4 bf16) per node, 8 nodes/block, 4-deep edge unroll.
// VGPR budget deliberate: 16 accs + 4 uint2 staging (round-3's 112-VGPR layout
// collapsed occupancy to 17%).

#define WESTR 132  // padded stride kills the 1.6M bank conflicts from round 3

__device__ __forceinline__ void accum4(float* a, uint2 v) {
    a[0] += __uint_as_float(v.x << 16);
    a[1] += __uint_as_float(v.x & 0xffff0000u);
    a[2] += __uint_as_float(v.y << 16);
    a[3] += __uint_as_float(v.y & 0xffff0000u);
}

__global__ __launch_bounds__(256) void agg_kernel(
    const int* __restrict__ row_ptr, const int* __restrict__ csr_s,
    const ushort_t* __restrict__ xm, const ushort_t* __restrict__ selfb,
    const float* __restrict__ segE, const float* __restrict__ We,
    const float* __restrict__ bm, const float* __restrict__ be,
    const float* __restrict__ sb, const float* __restrict__ degf,
    ushort_t* __restrict__ out, int n) {
    __shared__ float WeS[FE * WESTR];
    int tid = threadIdx.x;
    for (int i = tid; i < FE * HD; i += 256) {
        int k = i >> 7, c = i & 127;
        WeS[k * WESTR + c] = We[i];
    }
    __syncthreads();
    int node = blockIdx.x * 8 + (tid >> 5);
    if (node >= n) return;
    int c4 = (tid & 31) * 4;
    int beg = row_ptr[node], end = row_ptr[node + 1];
    float a0[4] = {0.f, 0.f, 0.f, 0.f};
    float a1[4] = {0.f, 0.f, 0.f, 0.f};
    float a2[4] = {0.f, 0.f, 0.f, 0.f};
    float a3[4] = {0.f, 0.f, 0.f, 0.f};
    int j = beg;
    for (; j + 3 < end; j += 4) {
        int u0 = csr_s[j], u1 = csr_s[j + 1], u2 = csr_s[j + 2], u3 = csr_s[j + 3];
        uint2 v0 = *(const uint2*)(xm + (size_t)u0 * HD + c4);
        uint2 v1 = *(const uint2*)(xm + (size_t)u1 * HD + c4);
        uint2 v2 = *(const uint2*)(xm + (size_t)u2 * HD + c4);
        uint2 v3 = *(const uint2*)(xm + (size_t)u3 * HD + c4);
        accum4(a0, v0);
        accum4(a1, v1);
        accum4(a2, v2);
        accum4(a3, v3);
    }
    for (; j < end; ++j) {
        int u = csr_s[j];
        uint2 v = *(const uint2*)(xm + (size_t)u * HD + c4);
        accum4(a0, v);
    }
    float dg = degf[node];
    const float* se = segE + (size_t)node * FE;
    float et[4];
#pragma unroll
    for (int i = 0; i < 4; ++i) et[i] = dg * (bm[c4 + i] + be[c4 + i]);
#pragma unroll
    for (int k = 0; k < FE; ++k) {
        float w = se[k];
#pragma unroll
        for (int i = 0; i < 4; ++i) et[i] += w * WeS[k * WESTR + c4 + i];
    }
    float sf[4];
    {
        uint2 sv = *(const uint2*)(selfb + (size_t)node * HD + c4);
        sf[0] = __uint_as_float(sv.x << 16);
        sf[1] = __uint_as_float(sv.x & 0xffff0000u);
        sf[2] = __uint_as_float(sv.y << 16);
        sf[3] = __uint_as_float(sv.y & 0xffff0000u);
    }
    ushort_t o[4];
#pragma unroll
    for (int i = 0; i < 4; ++i) {
        float r = (a0[i] + a1[i]) + (a2[i] + a3[i]) + et[i] + sf[i];
        if (sb) r += sb[c4 + i];
        o[i] = f2bf(fmaxf(r, 0.f));
    }
    *(uint2*)(out + (size_t)node * HD + c4) = *(uint2*)o;
}

// ---------------- mean pool (batch sorted): 4 partial blocks per graph ----------------

__global__ void pool_partial(const ushort_t* __restrict__ h, const int* __restrict__ batch,
                             float* __restrict__ pooled4) {
    int g = blockIdx.x;
    int q = blockIdx.y;
    int f = threadIdx.x;
    int lo = 0, hi = NN;
    while (lo < hi) { int m = (lo + hi) >> 1; if (batch[m] < g) lo = m + 1; else hi = m; }
    int s = lo;
    lo = s; hi = NN;
    while (lo < hi) { int m = (lo + hi) >> 1; if (batch[m] < g + 1) lo = m + 1; else hi = m; }
    int e = lo;
    int len = e - s;
    int c0 = s + (len * q) / 4;
    int c1 = s + (len * (q + 1)) / 4;
    float acc = 0.f;
    for (int v = c0; v < c1; ++v) acc += bf2f(h[(size_t)v * HD + f]);
    pooled4[((size_t)q * NG + g) * HD + f] = acc;
}

// ---------------- fusion head ----------------

__global__ void head_kernel(const float* __restrict__ pooled4, const int* __restrict__ batch,
                            const float* __restrict__ lf, const float* __restrict__ pfe,
                            const float* __restrict__ Wl, const float* __restrict__ bl,
                            const float* __restrict__ Wp, const float* __restrict__ bp,
                            const float* __restrict__ Wf, const float* __restrict__ bfv,
                            const float* __restrict__ Wo, const float* __restrict__ bo,
                            float* __restrict__ out) {
    __shared__ float cat[3 * HD];
    __shared__ float red[HD];
    int g = blockIdx.x, j = threadIdx.x;
    int lo = 0, hi = NN;
    while (lo < hi) { int m = (lo + hi) >> 1; if (batch[m] < g) lo = m + 1; else hi = m; }
    int s0 = lo;
    lo = s0; hi = NN;
    while (lo < hi) { int m = (lo + hi) >> 1; if (batch[m] < g + 1) lo = m + 1; else hi = m; }
    float cntf = (float)(lo - s0);
    float p = pooled4[(size_t)g * HD + j] + pooled4[((size_t)NG + g) * HD + j] +
              pooled4[((size_t)2 * NG + g) * HD + j] + pooled4[((size_t)3 * NG + g) * HD + j];
    cat[j] = p / fmaxf(cntf, 1.f);
    float s = bl[j];
    for (int k = 0; k < FL; ++k) s += lf[g * FL + k] * Wl[k * HD + j];
    cat[HD + j] = s;
    s = bp[j];
    for (int k = 0; k < FPOC; ++k) s += pfe[g * FPOC + k] * Wp[k * HD + j];
    cat[2 * HD + j] = s;
    __syncthreads();
    float fj = bfv[j];
    for (int k = 0; k < 3 * HD; ++k) fj += cat[k] * Wf[k * HD + j];
    red[j] = fj * Wo[j];
    __syncthreads();
    for (int off = 64; off > 0; off >>= 1) {
        if (j < off) red[j] += red[j + off];
        __syncthreads();
    }
    if (j == 0) out[g] = red[0] + bo[0];
}

// ---------------- launch ----------------

extern "C" void kernel_launch(void* const* d_in, const int* in_sizes, int n_in,
                              void* d_out, int out_size, void* d_ws, size_t ws_size,
                              hipStream_t stream) {
    const float* x       = (const float*)d_in[0];
    const int*   ei      = (const int*)d_in[1];
    const float* ea      = (const float*)d_in[2];
    const int*   batch   = (const int*)d_in[3];
    const float* lf      = (const float*)d_in[4];
    const float* pfe     = (const float*)d_in[5];
    const float* W1_msg  = (const float*)d_in[6];
    const float* b1_msg  = (const float*)d_in[7];
    const float* W1_edge = (const float*)d_in[8];
    const float* b1_edge = (const float*)d_in[9];
    const float* W1_self = (const float*)d_in[10];
    const float* b1_self = (const float*)d_in[11];
    const float* Wk_msg  = (const float*)d_in[12];
    const float* bk_msg  = (const float*)d_in[13];
    const float* Wk_edge = (const float*)d_in[14];
    const float* bk_edge = (const float*)d_in[15];
    const float* Wl      = (const float*)d_in[16];
    const float* bl      = (const float*)d_in[17];
    const float* Wp      = (const float*)d_in[18];
    const float* bp      = (const float*)d_in[19];
    const float* Wf      = (const float*)d_in[20];
    const float* bfv     = (const float*)d_in[21];
    const float* Wo      = (const float*)d_in[22];
    const float* bo      = (const float*)d_in[23];

    char* wsp = (char*)d_ws;
    size_t off = 0;
    auto carve = [&](size_t bytes) -> void* {
        char* p = wsp + off;
        off += (bytes + 255) & ~(size_t)255;
        return (void*)p;
    };
    int*      cnt     = (int*)carve((size_t)NN * 4);
    int*      row_ptr = (int*)carve((size_t)(NN + 1) * 4);
    int*      fillc   = (int*)carve((size_t)NN * 4);
    float*    degf    = (float*)carve((size_t)NN * 4);
    int*      csr_s   = (int*)carve((size_t)NE * 4);
    int*      csr_e   = (int*)carve((size_t)NE * 4);
    float*    segE    = (float*)carve((size_t)NN * FE * 4);
    ushort_t* xb      = (ushort_t*)carve((size_t)NN * FN * 2);
    ushort_t* pack    = (ushort_t*)carve((size_t)65536 * 2);
    ushort_t* bufA    = (ushort_t*)carve((size_t)NN * HD * 2);
    ushort_t* bufB    = (ushort_t*)carve((size_t)NN * HD * 2);
    ushort_t* bufC    = (ushort_t*)carve((size_t)NN * HD * 2);
    float*    pooled4 = (float*)carve((size_t)4 * NG * HD * 4);
    int*      bsum    = (int*)carve((size_t)256 * 4);
    int*      bpre    = (int*)carve((size_t)256 * 4);

    const int NBLK = (NN + 255) / 256;

    hipMemsetAsync(cnt, 0, (size_t)NN * 4, stream);
    hipMemsetAsync(fillc, 0, (size_t)NN * 4, stream);

    count_kernel<<<(NE + 255) / 256, 256, 0, stream>>>(ei, cnt);
    bsum_kernel<<<NBLK, 256, 0, stream>>>(cnt, bsum);
    bscan_kernel<<<1, 256, 0, stream>>>(bsum, bpre, NBLK);
    rowptr_kernel<<<NBLK, 256, 0, stream>>>(cnt, bpre, row_ptr, degf);
    fill_kernel<<<(NE + 255) / 256, 256, 0, stream>>>(ei, row_ptr, fillc, csr_s, csr_e);
    sege_kernel<<<(NN + 15) / 16, 256, 0, stream>>>(row_ptr, csr_e, ea, segE);
    cast_x_kernel<<<(NN * FN / 8 + 255) / 256, 256, 0, stream>>>(x, xb);
    repack_kernel<<<dim3(8, 5), 256, 0, stream>>>(W1_msg, W1_self, Wk_msg, pack);

    dim3 ggrid((NN + 63) / 64);
    // conv1: fused msg+self GEMM (shared A staging)
    gemm_mfma_conv1<<<ggrid, 256, 0, stream>>>(xb, pack, bufC, bufB, NN);
    agg_kernel<<<(NN + 7) / 8, 256, 0, stream>>>(row_ptr, csr_s, bufC, bufB, segE,
                                                 W1_edge, b1_msg, b1_edge, b1_self,
                                                 degf, bufA, NN);
    // stacked convs
    ushort_t* hcur = bufA;
    ushort_t* hnext = bufB;
    for (int i = 0; i < NSTACK; ++i) {
        gemm_mfma<128><<<ggrid, 256, 0, stream>>>(hcur, pack + 16384 + (size_t)i * 16384,
                                                  bufC, NN);
        agg_kernel<<<(NN + 7) / 8, 256, 0, stream>>>(row_ptr, csr_s, bufC, hcur, segE,
                                                     Wk_edge + (size_t)i * FE * HD,
                                                     bk_msg + i * HD, bk_edge + i * HD,
                                                     nullptr, degf, hnext, NN);
        ushort_t* t = hcur; hcur = hnext; hnext = t;
    }

    pool_partial<<<dim3(NG, 4), HD, 0, stream>>>(hcur, batch, pooled4);
    head_kernel<<<NG, HD, 0, stream>>>(pooled4, batch, lf, pfe, Wl, bl, Wp, bp, Wf, bfv,
                                       Wo, bo, (float*)d_out);
}

// Round 5
// 457.325 us; speedup vs baseline: 2.4835x; 1.2606x over previous
//
#include <hip/hip_runtime.h>
#include <cstdint>

#define NN 50000
#define NE 640000
#define NG 128
#define HD 128
#define FN 64
#define FE 16
#define FL 200
#define FPOC 100
#define NSTACK 3

typedef unsigned short ushort_t;
typedef short short8 __attribute__((ext_vector_type(8)));
typedef float f32x4 __attribute__((ext_vector_type(4)));

__device__ __forceinline__ ushort_t f2bf(float f) {
    unsigned u = __float_as_uint(f);
    unsigned r = (u + 0x7fffu + ((u >> 16) & 1u)) >> 16;
    return (ushort_t)r;
}
__device__ __forceinline__ float bf2f(ushort_t u) {
    return __uint_as_float(((unsigned)u) << 16);
}

// ---------------- CSR build ----------------

__global__ void count_kernel(const int* __restrict__ ei, int* __restrict__ cnt) {
    int e = blockIdx.x * 256 + threadIdx.x;
    if (e < NE) atomicAdd(&cnt[ei[NE + e]], 1);
}

__global__ void bsum_kernel(const int* __restrict__ cnt, int* __restrict__ bsum) {
    __shared__ int s[256];
    int t = threadIdx.x;
    int i = blockIdx.x * 256 + t;
    int v = (i < NN) ? cnt[i] : 0;
    s[t] = v;
    __syncthreads();
    for (int off = 128; off > 0; off >>= 1) {
        if (t < off) s[t] += s[t + off];
        __syncthreads();
    }
    if (t == 0) bsum[blockIdx.x] = s[0];
}

__global__ void bscan_kernel(const int* __restrict__ bsum, int* __restrict__ bpre, int nb) {
    __shared__ int s[256];
    int t = threadIdx.x;
    int v = (t < nb) ? bsum[t] : 0;
    s[t] = v;
    __syncthreads();
    for (int off = 1; off < 256; off <<= 1) {
        int w = (t >= off) ? s[t - off] : 0;
        __syncthreads();
        s[t] += w;
        __syncthreads();
    }
    if (t < nb) bpre[t] = s[t] - v;
}

__global__ void rowptr_kernel(const int* __restrict__ cnt, const int* __restrict__ bpre,
                              int* __restrict__ row_ptr, float* __restrict__ degf) {
    __shared__ int s[256];
    int t = threadIdx.x;
    int i = blockIdx.x * 256 + t;
    int v = (i < NN) ? cnt[i] : 0;
    s[t] = v;
    __syncthreads();
    for (int off = 1; off < 256; off <<= 1) {
        int w = (t >= off) ? s[t - off] : 0;
        __syncthreads();
        s[t] += w;
        __syncthreads();
    }
    if (i < NN) {
        row_ptr[i] = s[t] - v + bpre[blockIdx.x];
        degf[i] = (float)v;
    }
    if (i == 0) row_ptr[NN] = NE;
}

__global__ void fill_kernel(const int* __restrict__ ei, const int* __restrict__ row_ptr,
                            int* __restrict__ fill, int* __restrict__ csr_s,
                            int* __restrict__ csr_e) {
    int e = blockIdx.x * 256 + threadIdx.x;
    if (e < NE) {
        int s = ei[e];
        int d = ei[NE + e];
        int p = row_ptr[d] + atomicAdd(&fill[d], 1);
        csr_s[p] = s;
        csr_e[p] = e;
    }
}

__global__ __launch_bounds__(256) void sege_kernel(
    const int* __restrict__ row_ptr, const int* __restrict__ csr_e,
    const float* __restrict__ ea, float* __restrict__ segE) {
    int node = blockIdx.x * 16 + (threadIdx.x >> 4);
    int f = threadIdx.x & 15;
    if (node >= NN) return;
    int beg = row_ptr[node], end = row_ptr[node + 1];
    float a0 = 0.f, a1 = 0.f;
    int j = beg;
    for (; j + 1 < end; j += 2) {
        int e0 = csr_e[j], e1 = csr_e[j + 1];
        a0 += ea[(size_t)e0 * FE + f];
        a1 += ea[(size_t)e1 * FE + f];
    }
    if (j < end) a0 += ea[(size_t)csr_e[j] * FE + f];
    segE[node * FE + f] = a0 + a1;
}

// ---------------- fp32 -> bf16 cast for x ----------------

__global__ void cast_x_kernel(const float* __restrict__ x, ushort_t* __restrict__ xb) {
    int t = blockIdx.x * 256 + threadIdx.x;
    int base = t * 8;
    if (base >= NN * FN) return;
    float4 a = *(const float4*)(x + base);
    float4 b = *(const float4*)(x + base + 4);
    ushort_t o[8];
    o[0] = f2bf(a.x); o[1] = f2bf(a.y); o[2] = f2bf(a.z); o[3] = f2bf(a.w);
    o[4] = f2bf(b.x); o[5] = f2bf(b.y); o[6] = f2bf(b.z); o[7] = f2bf(b.w);
    *(uint4*)(xb + base) = *(uint4*)o;
}

// ---------------- weight repack into MFMA B-fragment order ----------------

__global__ void repack_kernel(const float* __restrict__ W1_msg,
                              const float* __restrict__ W1_self,
                              const float* __restrict__ Wk_msg,
                              ushort_t* __restrict__ pack) {
    int mid = blockIdx.y;
    const float* src;
    int K;
    size_t doff;
    if (mid == 0)      { src = W1_msg;  K = 64;  doff = 0; }
    else if (mid == 1) { src = W1_self; K = 64;  doff = 8192; }
    else               { src = Wk_msg + (size_t)(mid - 2) * HD * HD; K = 128;
                         doff = 16384 + (size_t)(mid - 2) * 16384; }
    int KS = K / 32;
    int t = blockIdx.x * 256 + threadIdx.x;
    if (t >= 8 * KS * 64) return;
    int lane = t & 63;
    int nk = t >> 6;
    int ks = nk % KS, nt = nk / KS;
    int n = nt * 16 + (lane & 15);
    int kb = ks * 32 + (lane >> 4) * 8;
    ushort_t o[8];
#pragma unroll
    for (int j = 0; j < 8; ++j) o[j] = f2bf(src[(size_t)(kb + j) * HD + n]);
    *(uint4*)(pack + doff + (size_t)t * 8) = *(uint4*)o;
}

// ---------------- MFMA GEMM: C[n,128] = A[n,K](bf16) @ Wpack, bf16 out ----------------

template <int K>
__global__ __launch_bounds__(256) void gemm_mfma(const ushort_t* __restrict__ A,
                                                 const ushort_t* __restrict__ Bp,
                                                 ushort_t* __restrict__ C, int n) {
    constexpr int KS = K / 32;
    constexpr int STR = K + 8;
    __shared__ __align__(16) ushort_t As[64 * STR];
    int tid = threadIdx.x;
    int row0 = blockIdx.x * 64;
    constexpr int CH = K / 8;
    constexpr int PASS = 64 * CH / 256;
#pragma unroll
    for (int p = 0; p < PASS; ++p) {
        int c = p * 256 + tid;
        int r = c / CH, col = c % CH;
        int gr = row0 + r;
        uint4 v = make_uint4(0u, 0u, 0u, 0u);
        if (gr < n) v = *(const uint4*)(A + (size_t)gr * K + col * 8);
        *(uint4*)(&As[r * STR + col * 8]) = v;
    }
    __syncthreads();
    int lane = tid & 63, wave = tid >> 6;
    int m = lane & 15, quad = lane >> 4;
    f32x4 acc[8];
#pragma unroll
    for (int i = 0; i < 8; ++i) acc[i] = (f32x4)(0.f);
    const short8* Bv = (const short8*)Bp;
#pragma unroll
    for (int ks = 0; ks < KS; ++ks) {
        short8 a = *(const short8*)(&As[(wave * 16 + m) * STR + ks * 32 + quad * 8]);
#pragma unroll
        for (int nt = 0; nt < 8; ++nt) {
            short8 b = Bv[(nt * KS + ks) * 64 + lane];
            acc[nt] = __builtin_amdgcn_mfma_f32_16x16x32_bf16(a, b, acc[nt], 0, 0, 0);
        }
    }
#pragma unroll
    for (int nt = 0; nt < 8; ++nt) {
#pragma unroll
        for (int r = 0; r < 4; ++r) {
            int grow = row0 + wave * 16 + quad * 4 + r;
            if (grow < n) C[(size_t)grow * HD + nt * 16 + m] = f2bf(acc[nt][r]);
        }
    }
}

// conv1 fused: one A-staging, 16 n-tiles (msg tiles 0..7 -> Cm, self tiles 8..15 -> Cs)
__global__ __launch_bounds__(256) void gemm_mfma_conv1(const ushort_t* __restrict__ A,
                                                       const ushort_t* __restrict__ Bp,
                                                       ushort_t* __restrict__ Cm,
                                                       ushort_t* __restrict__ Cs, int n) {
    constexpr int K = 64, KS = 2, STR = K + 8;
    __shared__ __align__(16) ushort_t As[64 * STR];
    int tid = threadIdx.x;
    int row0 = blockIdx.x * 64;
    constexpr int CH = K / 8;
    constexpr int PASS = 64 * CH / 256;
#pragma unroll
    for (int p = 0; p < PASS; ++p) {
        int c = p * 256 + tid;
        int r = c / CH, col = c % CH;
        int gr = row0 + r;
        uint4 v = make_uint4(0u, 0u, 0u, 0u);
        if (gr < n) v = *(const uint4*)(A + (size_t)gr * K + col * 8);
        *(uint4*)(&As[r * STR + col * 8]) = v;
    }
    __syncthreads();
    int lane = tid & 63, wave = tid >> 6;
    int m = lane & 15, quad = lane >> 4;
    f32x4 acc[16];
#pragma unroll
    for (int i = 0; i < 16; ++i) acc[i] = (f32x4)(0.f);
    const short8* Bv = (const short8*)Bp;
#pragma unroll
    for (int ks = 0; ks < KS; ++ks) {
        short8 a = *(const short8*)(&As[(wave * 16 + m) * STR + ks * 32 + quad * 8]);
#pragma unroll
        for (int nt = 0; nt < 16; ++nt) {
            short8 b = Bv[(nt * KS + ks) * 64 + lane];
            acc[nt] = __builtin_amdgcn_mfma_f32_16x16x32_bf16(a, b, acc[nt], 0, 0, 0);
        }
    }
#pragma unroll
    for (int nt = 0; nt < 16; ++nt) {
        ushort_t* dst = (nt < 8) ? Cm : Cs;
        int col = (nt & 7) * 16 + m;
#pragma unroll
        for (int r = 0; r < 4; ++r) {
            int grow = row0 + wave * 16 + quad * 4 + r;
            if (grow < n) dst[(size_t)grow * HD + col] = f2bf(acc[nt][r]);
        }
    }
}

// ---------------- fused aggregate (bf16 payload, fp32 accumulate) ----------------
// Shape rationale (rounds 2-4 post-mortems): latency-bound gather needs BOTH
// 16B/lane loads (uint4: full 256B row per 16-lane group, 1KB per wave-instr)
// AND low VGPR for occupancy. 2 acc sets (16 fp32) + 4 uint4 staging (16) keeps
// it ~64-72 VGPR vs round 3's 112 (4 acc sets -> 17% occupancy).

#define WESTR 136  // pad +8 floats: lane bank = (k*8 + c8) % 32, spreads across k

__device__ __forceinline__ void accum8(float* a, uint4 v) {
    a[0] += __uint_as_float(v.x << 16);
    a[1] += __uint_as_float(v.x & 0xffff0000u);
    a[2] += __uint_as_float(v.y << 16);
    a[3] += __uint_as_float(v.y & 0xffff0000u);
    a[4] += __uint_as_float(v.z << 16);
    a[5] += __uint_as_float(v.z & 0xffff0000u);
    a[6] += __uint_as_float(v.w << 16);
    a[7] += __uint_as_float(v.w & 0xffff0000u);
}

__global__ __launch_bounds__(256, 6) void agg_kernel(
    const int* __restrict__ row_ptr, const int* __restrict__ csr_s,
    const ushort_t* __restrict__ xm, const ushort_t* __restrict__ selfb,
    const float* __restrict__ segE, const float* __restrict__ We,
    const float* __restrict__ bm, const float* __restrict__ be,
    const float* __restrict__ sb, const float* __restrict__ degf,
    ushort_t* __restrict__ out, int n) {
    __shared__ float WeS[FE * WESTR];
    int tid = threadIdx.x;
    for (int i = tid; i < FE * HD; i += 256) {
        int k = i >> 7, c = i & 127;
        WeS[k * WESTR + c] = We[i];
    }
    __syncthreads();
    int node = blockIdx.x * 16 + (tid >> 4);
    if (node >= n) return;
    int c8 = (tid & 15) * 8;
    int beg = row_ptr[node], end = row_ptr[node + 1];
    float a0[8] = {0.f, 0.f, 0.f, 0.f, 0.f, 0.f, 0.f, 0.f};
    float a1[8] = {0.f, 0.f, 0.f, 0.f, 0.f, 0.f, 0.f, 0.f};
    int j = beg;
    for (; j + 3 < end; j += 4) {
        int u0 = csr_s[j], u1 = csr_s[j + 1], u2 = csr_s[j + 2], u3 = csr_s[j + 3];
        uint4 v0 = *(const uint4*)(xm + (size_t)u0 * HD + c8);
        uint4 v1 = *(const uint4*)(xm + (size_t)u1 * HD + c8);
        uint4 v2 = *(const uint4*)(xm + (size_t)u2 * HD + c8);
        uint4 v3 = *(const uint4*)(xm + (size_t)u3 * HD + c8);
        accum8(a0, v0);
        accum8(a1, v1);
        accum8(a0, v2);
        accum8(a1, v3);
    }
    for (; j < end; ++j) {
        int u = csr_s[j];
        uint4 v = *(const uint4*)(xm + (size_t)u * HD + c8);
        accum8(a0, v);
    }
    // epilogue folds into a0
    float dg = degf[node];
    const float* se = segE + (size_t)node * FE;
#pragma unroll
    for (int i = 0; i < 8; ++i) a0[i] += a1[i] + dg * (bm[c8 + i] + be[c8 + i]);
#pragma unroll
    for (int k = 0; k < FE; ++k) {
        float w = se[k];
#pragma unroll
        for (int i = 0; i < 8; ++i) a0[i] += w * WeS[k * WESTR + c8 + i];
    }
    {
        uint4 sv = *(const uint4*)(selfb + (size_t)node * HD + c8);
        accum8(a0, sv);
    }
    if (sb) {
#pragma unroll
        for (int i = 0; i < 8; ++i) a0[i] += sb[c8 + i];
    }
    ushort_t o[8];
#pragma unroll
    for (int i = 0; i < 8; ++i) o[i] = f2bf(fmaxf(a0[i], 0.f));
    *(uint4*)(out + (size_t)node * HD + c8) = *(uint4*)o;
}

// ---------------- mean pool (batch sorted): 4 partial blocks per graph ----------------

__global__ void pool_partial(const ushort_t* __restrict__ h, const int* __restrict__ batch,
                             float* __restrict__ pooled4) {
    int g = blockIdx.x;
    int q = blockIdx.y;
    int f = threadIdx.x;
    int lo = 0, hi = NN;
    while (lo < hi) { int m = (lo + hi) >> 1; if (batch[m] < g) lo = m + 1; else hi = m; }
    int s = lo;
    lo = s; hi = NN;
    while (lo < hi) { int m = (lo + hi) >> 1; if (batch[m] < g + 1) lo = m + 1; else hi = m; }
    int e = lo;
    int len = e - s;
    int c0 = s + (len * q) / 4;
    int c1 = s + (len * (q + 1)) / 4;
    float acc = 0.f;
    for (int v = c0; v < c1; ++v) acc += bf2f(h[(size_t)v * HD + f]);
    pooled4[((size_t)q * NG + g) * HD + f] = acc;
}

// ---------------- fusion head ----------------

__global__ void head_kernel(const float* __restrict__ pooled4, const int* __restrict__ batch,
                            const float* __restrict__ lf, const float* __restrict__ pfe,
                            const float* __restrict__ Wl, const float* __restrict__ bl,
                            const float* __restrict__ Wp, const float* __restrict__ bp,
                            const float* __restrict__ Wf, const float* __restrict__ bfv,
                            const float* __restrict__ Wo, const float* __restrict__ bo,
                            float* __restrict__ out) {
    __shared__ float cat[3 * HD];
    __shared__ float red[HD];
    int g = blockIdx.x, j = threadIdx.x;
    int lo = 0, hi = NN;
    while (lo < hi) { int m = (lo + hi) >> 1; if (batch[m] < g) lo = m + 1; else hi = m; }
    int s0 = lo;
    lo = s0; hi = NN;
    while (lo < hi) { int m = (lo + hi) >> 1; if (batch[m] < g + 1) lo = m + 1; else hi = m; }
    float cntf = (float)(lo - s0);
    float p = pooled4[(size_t)g * HD + j] + pooled4[((size_t)NG + g) * HD + j] +
              pooled4[((size_t)2 * NG + g) * HD + j] + pooled4[((size_t)3 * NG + g) * HD + j];
    cat[j] = p / fmaxf(cntf, 1.f);
    float s = bl[j];
    for (int k = 0; k < FL; ++k) s += lf[g * FL + k] * Wl[k * HD + j];
    cat[HD + j] = s;
    s = bp[j];
    for (int k = 0; k < FPOC; ++k) s += pfe[g * FPOC + k] * Wp[k * HD + j];
    cat[2 * HD + j] = s;
    __syncthreads();
    float fj = bfv[j];
    for (int k = 0; k < 3 * HD; ++k) fj += cat[k] * Wf[k * HD + j];
    red[j] = fj * Wo[j];
    __syncthreads();
    for (int off = 64; off > 0; off >>= 1) {
        if (j < off) red[j] += red[j + off];
        __syncthreads();
    }
    if (j == 0) out[g] = red[0] + bo[0];
}

// ---------------- launch ----------------

extern "C" void kernel_launch(void* const* d_in, const int* in_sizes, int n_in,
                              void* d_out, int out_size, void* d_ws, size_t ws_size,
                              hipStream_t stream) {
    const float* x       = (const float*)d_in[0];
    const int*   ei      = (const int*)d_in[1];
    const float* ea      = (const float*)d_in[2];
    const int*   batch   = (const int*)d_in[3];
    const float* lf      = (const float*)d_in[4];
    const float* pfe     = (const float*)d_in[5];
    const float* W1_msg  = (const float*)d_in[6];
    const float* b1_msg  = (const float*)d_in[7];
    const float* W1_edge = (const float*)d_in[8];
    const float* b1_edge = (const float*)d_in[9];
    const float* W1_self = (const float*)d_in[10];
    const float* b1_self = (const float*)d_in[11];
    const float* Wk_msg  = (const float*)d_in[12];
    const float* bk_msg  = (const float*)d_in[13];
    const float* Wk_edge = (const float*)d_in[14];
    const float* bk_edge = (const float*)d_in[15];
    const float* Wl      = (const float*)d_in[16];
    const float* bl      = (const float*)d_in[17];
    const float* Wp      = (const float*)d_in[18];
    const float* bp      = (const float*)d_in[19];
    const float* Wf      = (const float*)d_in[20];
    const float* bfv     = (const float*)d_in[21];
    const float* Wo      = (const float*)d_in[22];
    const float* bo      = (const float*)d_in[23];

    char* wsp = (char*)d_ws;
    size_t off = 0;
    auto carve = [&](size_t bytes) -> void* {
        char* p = wsp + off;
        off += (bytes + 255) & ~(size_t)255;
        return (void*)p;
    };
    int*      cnt     = (int*)carve((size_t)NN * 4);
    int*      row_ptr = (int*)carve((size_t)(NN + 1) * 4);
    int*      fillc   = (int*)carve((size_t)NN * 4);
    float*    degf    = (float*)carve((size_t)NN * 4);
    int*      csr_s   = (int*)carve((size_t)NE * 4);
    int*      csr_e   = (int*)carve((size_t)NE * 4);
    float*    segE    = (float*)carve((size_t)NN * FE * 4);
    ushort_t* xb      = (ushort_t*)carve((size_t)NN * FN * 2);
    ushort_t* pack    = (ushort_t*)carve((size_t)65536 * 2);
    ushort_t* bufA    = (ushort_t*)carve((size_t)NN * HD * 2);
    ushort_t* bufB    = (ushort_t*)carve((size_t)NN * HD * 2);
    ushort_t* bufC    = (ushort_t*)carve((size_t)NN * HD * 2);
    float*    pooled4 = (float*)carve((size_t)4 * NG * HD * 4);
    int*      bsum    = (int*)carve((size_t)256 * 4);
    int*      bpre    = (int*)carve((size_t)256 * 4);

    const int NBLK = (NN + 255) / 256;

    hipMemsetAsync(cnt, 0, (size_t)NN * 4, stream);
    hipMemsetAsync(fillc, 0, (size_t)NN * 4, stream);

    count_kernel<<<(NE + 255) / 256, 256, 0, stream>>>(ei, cnt);
    bsum_kernel<<<NBLK, 256, 0, stream>>>(cnt, bsum);
    bscan_kernel<<<1, 256, 0, stream>>>(bsum, bpre, NBLK);
    rowptr_kernel<<<NBLK, 256, 0, stream>>>(cnt, bpre, row_ptr, degf);
    fill_kernel<<<(NE + 255) / 256, 256, 0, stream>>>(ei, row_ptr, fillc, csr_s, csr_e);
    sege_kernel<<<(NN + 15) / 16, 256, 0, stream>>>(row_ptr, csr_e, ea, segE);
    cast_x_kernel<<<(NN * FN / 8 + 255) / 256, 256, 0, stream>>>(x, xb);
    repack_kernel<<<dim3(8, 5), 256, 0, stream>>>(W1_msg, W1_self, Wk_msg, pack);

    dim3 ggrid((NN + 63) / 64);
    gemm_mfma_conv1<<<ggrid, 256, 0, stream>>>(xb, pack, bufC, bufB, NN);
    agg_kernel<<<(NN + 15) / 16, 256, 0, stream>>>(row_ptr, csr_s, bufC, bufB, segE,
                                                   W1_edge, b1_msg, b1_edge, b1_self,
                                                   degf, bufA, NN);
    ushort_t* hcur = bufA;
    ushort_t* hnext = bufB;
    for (int i = 0; i < NSTACK; ++i) {
        gemm_mfma<128><<<ggrid, 256, 0, stream>>>(hcur, pack + 16384 + (size_t)i * 16384,
                                                  bufC, NN);
        agg_kernel<<<(NN + 15) / 16, 256, 0, stream>>>(row_ptr, csr_s, bufC, hcur, segE,
                                                       Wk_edge + (size_t)i * FE * HD,
                                                       bk_msg + i * HD, bk_edge + i * HD,
                                                       nullptr, degf, hnext, NN);
        ushort_t* t = hcur; hcur = hnext; hnext = t;
    }

    pool_partial<<<dim3(NG, 4), HD, 0, stream>>>(hcur, batch, pooled4);
    head_kernel<<<NG, HD, 0, stream>>>(pooled4, batch, lf, pfe, Wl, bl, Wp, bp, Wf, bfv,
                                       Wo, bo, (float*)d_out);
}